// Round 5
// baseline (101.843 us; speedup 1.0000x reference)
//
#include <hip/hip_runtime.h>
#include <hip/hip_bf16.h>

#define T_TOK 512
#define H_DIM 2048
#define E_NUM 8
#define I_DIM 1024

typedef __attribute__((ext_vector_type(8))) short short8;
typedef __attribute__((ext_vector_type(4))) float f32x4;

// round-to-nearest-even float -> bf16 (as ushort)
__device__ __forceinline__ unsigned short f2bf(float f) {
    unsigned int u = __float_as_uint(f);
    u += 0x7fff + ((u >> 16) & 1);
    return (unsigned short)(u >> 16);
}

// 8 fp32 -> short8 of bf16 via packed cvt (RNE)
__device__ __forceinline__ short8 cvt8(float4 a, float4 b) {
    union { short8 s; __hip_bfloat162 h[4]; } u;
    u.h[0] = __float22bfloat162_rn(make_float2(a.x, a.y));
    u.h[1] = __float22bfloat162_rn(make_float2(a.z, a.w));
    u.h[2] = __float22bfloat162_rn(make_float2(b.x, b.y));
    u.h[3] = __float22bfloat162_rn(make_float2(b.z, b.w));
    return u.s;
}

// async global->LDS, 16B per lane; lds dest is wave-uniform base + lane*16
__device__ __forceinline__ void gload_lds16(const void* g, void* l) {
    __builtin_amdgcn_global_load_lds(
        (const __attribute__((address_space(1))) void*)g,
        (__attribute__((address_space(3))) void*)l, 16, 0, 0);
}

// ---------------------------------------------------------------
// Kernel 0: x -> bf16 (1M elems, 8/thread)
// ---------------------------------------------------------------
__global__ __launch_bounds__(256) void xcvt_kernel(
    const float* __restrict__ x, unsigned short* __restrict__ xb)
{
    int i = (blockIdx.x * 256 + threadIdx.x) * 8;
    float4 v0 = *(const float4*)(x + i);
    float4 v1 = *(const float4*)(x + i + 4);
    *(short8*)(xb + i) = cvt8(v0, v1);
}

// ---------------------------------------------------------------
// Kernel 1: routing. 1 block, 512 threads.
// ---------------------------------------------------------------
__global__ __launch_bounds__(512) void routing_kernel(
    const float* __restrict__ logits,
    int* __restrict__ count, int* __restrict__ bucket,
    float* __restrict__ pair_w)
{
    int t = threadIdx.x;
    if (t < E_NUM) count[t] = 0;
    __syncthreads();

    float p[E_NUM];
    float m = -INFINITY;
#pragma unroll
    for (int e = 0; e < E_NUM; ++e) {
        p[e] = logits[t * E_NUM + e];
        m = fmaxf(m, p[e]);
    }
#pragma unroll
    for (int e = 0; e < E_NUM; ++e) p[e] = expf(p[e] - m);
    int i0 = 0;
#pragma unroll
    for (int e = 1; e < E_NUM; ++e) if (p[e] > p[i0]) i0 = e;
    int i1 = (i0 == 0) ? 1 : 0;
#pragma unroll
    for (int e = 0; e < E_NUM; ++e) if (e != i0 && p[e] > p[i1]) i1 = e;
    float denom = p[i0] + p[i1];
    pair_w[2 * t + 0] = p[i0] / denom;
    pair_w[2 * t + 1] = p[i1] / denom;

    int pos0 = atomicAdd(&count[i0], 1);
    bucket[i0 * T_TOK + pos0] = 2 * t + 0;
    int pos1 = atomicAdd(&count[i1], 1);
    bucket[i1 * T_TOK + pos1] = 2 * t + 1;
}

// ---------------------------------------------------------------
// Kernel 2: grouped GEMM1 + SiLU. BM=64, BN=32(gate)+32(up), BK=32.
// Ring-4 LDS (48 KB), 3 tiles in flight (vmcnt(9) counted, never 0
// in-loop). A = x_bf16 (linear LDS, conflict-free contiguous frag
// reads); G/U = w13 fp32, granule-XOR swizzle, cvt at read.
// 4 waves 2x2: wave = 32 rows x (16 gate + 16 up cols).
// ---------------------------------------------------------------
__global__ __launch_bounds__(256) void gemm1_silu_kernel(
    const unsigned short* __restrict__ xb, const float* __restrict__ w13,
    const int* __restrict__ count, const int* __restrict__ bucket,
    __hip_bfloat16* __restrict__ act)
{
    const int e   = blockIdx.z;
    const int n_e = count[e];
    const int m0  = blockIdx.y * 64;
    if (m0 >= n_e) return;
    const int n0  = blockIdx.x * 32;

    __shared__ unsigned short sA[4][64 * 32];  // bf16 4 KB/buf
    __shared__ float sG[4][32 * 32];           // f32  4 KB/buf
    __shared__ float sU[4][32 * 32];           // f32  4 KB/buf

    const int tid  = threadIdx.x;
    const int lane = tid & 63;
    const int wid  = tid >> 6;
    const int fr   = lane & 15;
    const int fq   = lane >> 4;
    const int wr   = wid >> 1;
    const int wc   = wid & 1;

    // A staging: 1 instr/wave = 16 rows x 64 B (linear, no swizzle)
    const int arow = 16 * wid + (lane >> 2);
    const int tok  = bucket[e * T_TOK + min(m0 + arow, n_e - 1)] >> 1;
    const unsigned short* aptr = xb + (size_t)tok * H_DIM + (lane & 3) * 8;
    // G/U staging: 1 instr/wave = 8 rows x 128 B, source pre-swizzled
    const int grow = 8 * wid + (lane >> 3);
    const int gs   = (lane & 7) ^ (lane >> 3);
    const float* gptr = w13 + ((size_t)e * (2 * I_DIM) + n0 + grow) * H_DIM + gs * 4;
    const float* uptr = w13 + ((size_t)e * (2 * I_DIM) + I_DIM + n0 + grow) * H_DIM + gs * 4;

    auto stage = [&](int kb, int buf) {
        gload_lds16(aptr + kb, &sA[buf][16 * wid * 32]);
        gload_lds16(gptr + kb, &sG[buf][8 * wid * 32]);
        gload_lds16(uptr + kb, &sU[buf][8 * wid * 32]);
    };

    f32x4 accg[2] = {};
    f32x4 accu[2] = {};

    stage(0, 0); stage(32, 1); stage(64, 2);

    for (int t = 0; t < 64; ++t) {
        stage(min((t + 3) * 32, 2016), (t + 3) & 3);   // clamped fake tail-stages keep loop uniform
        asm volatile("s_waitcnt vmcnt(9)" ::: "memory");   // tile t landed (3 newer in flight)
        __builtin_amdgcn_s_barrier();

        const int buf = t & 3;
        short8 a[2], bg, bu;
#pragma unroll
        for (int m = 0; m < 2; ++m)
            a[m] = *(const short8*)&sA[buf][(wr * 32 + m * 16 + fr) * 32 + fq * 8];
        {
            int r  = wc * 16 + fr;
            int s0 = (fq * 2) ^ (r & 7);
            const float* gb = &sG[buf][r * 32];
            bg = cvt8(*(const float4*)(gb + s0 * 4), *(const float4*)(gb + (s0 ^ 1) * 4));
            const float* ub = &sU[buf][r * 32];
            bu = cvt8(*(const float4*)(ub + s0 * 4), *(const float4*)(ub + (s0 ^ 1) * 4));
        }
        asm volatile("s_waitcnt lgkmcnt(0)" ::: "memory");  // reads retired
        __builtin_amdgcn_s_barrier();                       // buffer free for reuse

        accg[0] = __builtin_amdgcn_mfma_f32_16x16x32_bf16(a[0], bg, accg[0], 0, 0, 0);
        accg[1] = __builtin_amdgcn_mfma_f32_16x16x32_bf16(a[1], bg, accg[1], 0, 0, 0);
        accu[0] = __builtin_amdgcn_mfma_f32_16x16x32_bf16(a[0], bu, accu[0], 0, 0, 0);
        accu[1] = __builtin_amdgcn_mfma_f32_16x16x32_bf16(a[1], bu, accu[1], 0, 0, 0);
    }
    asm volatile("s_waitcnt vmcnt(0)" ::: "memory");   // drain fakes before exit

    // epilogue: silu(gate)*up -> act (bf16)
#pragma unroll
    for (int m = 0; m < 2; ++m) {
#pragma unroll
        for (int j = 0; j < 4; ++j) {
            int r = m0 + wr * 32 + m * 16 + fq * 4 + j;
            if (r < n_e) {
                int pid = bucket[e * T_TOK + r];
                float g = accg[m][j];
                float u = accu[m][j];
                float sg = g / (1.f + expf(-g));
                int col = n0 + wc * 16 + fr;
                *(unsigned short*)(act + (size_t)pid * I_DIM + col) = f2bf(sg * u);
            }
        }
    }
}

// ---------------------------------------------------------------
// Kernel 3: grouped GEMM2. BM=64, BN=32, BK=64. Ring-4 (64 KB),
// vmcnt(12) counted. A = act bf16 (swizzled), B = w2 fp32 (swizzled,
// cvt at read). 4 waves 2x2: wave = 32 rows x 16 cols.
// ---------------------------------------------------------------
__global__ __launch_bounds__(256) void gemm2_kernel(
    const __hip_bfloat16* __restrict__ act, const float* __restrict__ w2,
    const int* __restrict__ count, const int* __restrict__ bucket,
    float* __restrict__ y)
{
    const int e   = blockIdx.z;
    const int n_e = count[e];
    const int m0  = blockIdx.y * 64;
    if (m0 >= n_e) return;
    const int h0  = blockIdx.x * 32;

    __shared__ unsigned short sA[4][64 * 64];  // bf16 8 KB/buf
    __shared__ float sB[4][32 * 64];           // f32  8 KB/buf

    const int tid  = threadIdx.x;
    const int lane = tid & 63;
    const int wid  = tid >> 6;
    const int fr   = lane & 15;
    const int fq   = lane >> 4;
    const int wr   = wid >> 1;
    const int wc   = wid & 1;

    // A staging: 2 instr/wave, each 8 rows x 128 B, swizzled source
    const unsigned short* aptr[2];
#pragma unroll
    for (int i = 0; i < 2; ++i) {
        int r   = 16 * wid + 8 * i + (lane >> 3);
        int gsl = (lane & 7) ^ (r & 7);
        int pid = bucket[e * T_TOK + min(m0 + r, n_e - 1)];
        aptr[i] = (const unsigned short*)act + (size_t)pid * I_DIM + gsl * 8;
    }
    // B staging: 2 instr/wave, each 4 rows x 256 B, swizzled source
    const float* bptr[2];
#pragma unroll
    for (int i = 0; i < 2; ++i) {
        int r   = 8 * wid + 4 * i + (lane >> 4);
        int gsl = (lane & 15) ^ (r & 7);
        bptr[i] = w2 + ((size_t)e * H_DIM + h0 + r) * I_DIM + gsl * 4;
    }

    auto stage = [&](int kb, int buf) {
#pragma unroll
        for (int i = 0; i < 2; ++i)
            gload_lds16(aptr[i] + kb, &sA[buf][(16 * wid + 8 * i) * 64]);
#pragma unroll
        for (int i = 0; i < 2; ++i)
            gload_lds16(bptr[i] + kb, &sB[buf][(8 * wid + 4 * i) * 64]);
    };

    f32x4 acc[2] = {};

    stage(0, 0); stage(64, 1); stage(128, 2);

    for (int t = 0; t < 16; ++t) {
        stage(min((t + 3) * 64, 960), (t + 3) & 3);
        asm volatile("s_waitcnt vmcnt(12)" ::: "memory");
        __builtin_amdgcn_s_barrier();

        const int buf = t & 3;
        short8 a[2][2], b[2];
#pragma unroll
        for (int kk = 0; kk < 2; ++kk) {
#pragma unroll
            for (int m = 0; m < 2; ++m) {
                int r    = wr * 32 + m * 16 + fr;
                int slot = (kk * 4 + fq) ^ (r & 7);
                a[kk][m] = *(const short8*)&sA[buf][r * 64 + slot * 8];
            }
            {
                int r  = wc * 16 + fr;
                int s0 = (kk * 8 + fq * 2) ^ (r & 7);
                const float* bb = &sB[buf][r * 64];
                b[kk] = cvt8(*(const float4*)(bb + s0 * 4), *(const float4*)(bb + (s0 ^ 1) * 4));
            }
        }
        asm volatile("s_waitcnt lgkmcnt(0)" ::: "memory");
        __builtin_amdgcn_s_barrier();

#pragma unroll
        for (int kk = 0; kk < 2; ++kk)
#pragma unroll
            for (int m = 0; m < 2; ++m)
                acc[m] = __builtin_amdgcn_mfma_f32_16x16x32_bf16(a[kk][m], b[kk], acc[m], 0, 0, 0);
    }
    asm volatile("s_waitcnt vmcnt(0)" ::: "memory");

#pragma unroll
    for (int m = 0; m < 2; ++m) {
#pragma unroll
        for (int j = 0; j < 4; ++j) {
            int r = m0 + wr * 32 + m * 16 + fq * 4 + j;
            if (r < n_e) {
                int pid = bucket[e * T_TOK + r];
                y[(size_t)pid * H_DIM + h0 + wc * 16 + fr] = acc[m][j];
            }
        }
    }
}

// ---------------------------------------------------------------
// Kernel 4: combine. out[t,h] = w0*y[2t,h] + w1*y[2t+1,h]
// ---------------------------------------------------------------
__global__ __launch_bounds__(256) void combine_kernel(
    const float* __restrict__ y, const float* __restrict__ pair_w,
    float* __restrict__ out)
{
    int idx = blockIdx.x * 256 + threadIdx.x;
    int t = idx >> 9;
    int c = idx & 511;
    float w0 = pair_w[2 * t + 0];
    float w1 = pair_w[2 * t + 1];
    float4 y0 = ((const float4*)(y + (size_t)(2 * t + 0) * H_DIM))[c];
    float4 y1 = ((const float4*)(y + (size_t)(2 * t + 1) * H_DIM))[c];
    float4 o;
    o.x = w0 * y0.x + w1 * y1.x;
    o.y = w0 * y0.y + w1 * y1.y;
    o.z = w0 * y0.z + w1 * y1.z;
    o.w = w0 * y0.w + w1 * y1.w;
    ((float4*)(out + (size_t)t * H_DIM))[c] = o;
}

extern "C" void kernel_launch(void* const* d_in, const int* in_sizes, int n_in,
                              void* d_out, int out_size, void* d_ws, size_t ws_size,
                              hipStream_t stream) {
    const float* x      = (const float*)d_in[0];
    const float* logits = (const float*)d_in[1];
    const float* w13    = (const float*)d_in[2];
    const float* w2     = (const float*)d_in[3];
    float* out = (float*)d_out;

    // workspace layout (16B-aligned sections)
    int*   count  = (int*)d_ws;                                        // 8 (+pad to 8)
    int*   bucket = count + E_NUM;                                     // 4096
    float* pair_w = (float*)(bucket + E_NUM * T_TOK);                  // 1024
    unsigned short* xb = (unsigned short*)(pair_w + 2 * T_TOK);        // 512*2048 bf16 (2 MB)
    __hip_bfloat16* act = (__hip_bfloat16*)(xb + (size_t)T_TOK * H_DIM);   // 1024*1024 bf16 (2 MB)
    float* ybuf   = (float*)((unsigned short*)act + (size_t)2 * T_TOK * I_DIM); // 1024*2048 f32 (8 MB)

    xcvt_kernel<<<(T_TOK * H_DIM / 8) / 256, 256, 0, stream>>>(x, xb);
    routing_kernel<<<1, 512, 0, stream>>>(logits, count, bucket, pair_w);
    gemm1_silu_kernel<<<dim3(I_DIM / 32, T_TOK / 64, E_NUM), 256, 0, stream>>>(
        xb, w13, count, bucket, act);
    gemm2_kernel<<<dim3(H_DIM / 32, T_TOK / 64, E_NUM), 256, 0, stream>>>(
        act, w2, count, bucket, ybuf);
    combine_kernel<<<(T_TOK * (H_DIM / 4)) / 256, 256, 0, stream>>>(
        ybuf, pair_w, out);
}